// Round 3
// baseline (108.121 us; speedup 1.0000x reference)
//
#include <hip/hip_runtime.h>
#include <hip/hip_cooperative_groups.h>
#include <math.h>

namespace cg = cooperative_groups;

#define NN 384
#define DD 128
#define NB 256
#define NT 256
#define NTILE (NN / 16)            // 24
#define EPSF 1e-6f

__global__ void __launch_bounds__(NT) k_fused(const float* __restrict__ X,
                                              const float* __restrict__ G,
                                              const int* __restrict__ y,
                                              float* __restrict__ A,
                                              float* __restrict__ prod,
                                              float* __restrict__ p2,
                                              float* __restrict__ csmd,
                                              float* __restrict__ invd,
                                              float* __restrict__ out) {
    cg::grid_group grid = cg::this_grid();
    const int b = blockIdx.x;
    const int t = threadIdx.x;

    __shared__ float Xi[DD];
    __shared__ float Bp[2][DD];
    __shared__ float Ap[2][DD];
    __shared__ float Ai[16][20], Xk[16][20], Ak[16][20];
    __shared__ float cvals[NN];
    __shared__ int   jidx[NN];
    __shared__ float red[NT];
    __shared__ int   cnt;

    // ================= Phase 1: A = (X G^T) G, prod[i]=X_i.A_i, p2[i]=A_i.A_i
    for (int i = b; i < NN; i += NB) {
        if (t < DD / 4) ((float4*)Xi)[t] = ((const float4*)(X + (size_t)i * DD))[t];
        __syncthreads();
        const int h = t >> 7;            // d/c half: waves 0-1 -> 0, waves 2-3 -> 1
        const int c = t & (DD - 1);
        // pass 1: B[c] = sum_d X_i[d] * G[c][d]   (half-d per thread)
        float acc = 0.f;
        const float* gr = G + (size_t)c * DD + 64 * h;
        const float* xr = Xi + 64 * h;
#pragma unroll
        for (int d = 0; d < 64; d += 4) {
            float4 g = *(const float4*)(gr + d);
            acc = fmaf(g.x, xr[d + 0], acc);
            acc = fmaf(g.y, xr[d + 1], acc);
            acc = fmaf(g.z, xr[d + 2], acc);
            acc = fmaf(g.w, xr[d + 3], acc);
        }
        Bp[h][c] = acc;
        __syncthreads();
        if (t < DD) Bp[0][t] += Bp[1][t];
        __syncthreads();
        // pass 2: A_i[d] = sum_c B[c] * G[c][d]   (half-c per thread, coalesced G)
        float a = 0.f;
        {
            const int cbeg = 64 * h;
#pragma unroll 4
            for (int cc = cbeg; cc < cbeg + 64; ++cc)
                a = fmaf(Bp[0][cc], G[(size_t)cc * DD + c], a);
        }
        Ap[h][c] = a;
        __syncthreads();
        float pp = 0.f, qq = 0.f;
        float av = 0.f;
        if (t < DD) {
            av = Ap[0][t] + Ap[1][t];
            A[(size_t)i * DD + t] = av;
            pp = av * Xi[t];
            qq = av * av;
        }
        __syncthreads();               // Ap reads done
        if (t < DD) { Ap[0][t] = pp; Ap[1][t] = qq; }
        __syncthreads();
        if (t < 64) {                  // single wave: shuffle-reduce 128 values
            float v = Ap[0][t] + Ap[0][t + 64];
            float w = Ap[1][t] + Ap[1][t + 64];
#pragma unroll
            for (int off = 32; off > 0; off >>= 1) {
                v += __shfl_down(v, off);
                w += __shfl_down(w, off);
            }
            if (t == 0) { prod[i] = v; p2[i] = w; }
        }
        __syncthreads();               // protect Xi/Bp/Ap for next row
    }

    grid.sync();

    // ================= Phase 2: csmd + invd (16x16 tiles)
    {
        const int tx = t & 15, ty = t >> 4;
        for (int tid = b; tid < NTILE * NTILE; tid += NB) {
            const int i0 = (tid / NTILE) * 16;
            const int k0 = (tid % NTILE) * 16;
            float dA = 0.f, dAA = 0.f;
            for (int d0 = 0; d0 < DD; d0 += 16) {
                Ai[ty][tx] = A[(size_t)(i0 + ty) * DD + d0 + tx];
                Xk[ty][tx] = X[(size_t)(k0 + ty) * DD + d0 + tx];
                Ak[ty][tx] = A[(size_t)(k0 + ty) * DD + d0 + tx];
                __syncthreads();
#pragma unroll
                for (int t4 = 0; t4 < 16; t4 += 4) {
                    float4 aa = *(const float4*)&Ai[ty][t4];
                    float4 xx = *(const float4*)&Xk[tx][t4];
                    float4 ak = *(const float4*)&Ak[tx][t4];
                    dA  = fmaf(aa.x, xx.x, dA);  dA  = fmaf(aa.y, xx.y, dA);
                    dA  = fmaf(aa.z, xx.z, dA);  dA  = fmaf(aa.w, xx.w, dA);
                    dAA = fmaf(aa.x, ak.x, dAA); dAA = fmaf(aa.y, ak.y, dAA);
                    dAA = fmaf(aa.z, ak.z, dAA); dAA = fmaf(aa.w, ak.w, dAA);
                }
                __syncthreads();
            }
            const int i = i0 + ty, k = k0 + tx;
            float c1 = prod[i] + prod[k] - 2.f * dA;
            csmd[(size_t)i * NN + k] = c1;
            float c2 = p2[i] + p2[k] - 2.f * dAA;
            float den = fmaxf(2.f * sqrtf(fmaxf(c2, EPSF)), EPSF);
            invd[(size_t)i * NN + k] = 1.f / den;
        }
    }

    grid.sync();

    // ================= Phase 3: out[i] = min_k max_j relu(c_ik - c_ij) * invd[j,k]
    for (int i = b; i < NN; i += NB) {
        const int yi = y[i];
        if (t == 0) cnt = 0;
        __syncthreads();
        const float cit0 = csmd[(size_t)i * NN + t];
        const int   yt0  = y[t];
        float cit1 = 0.f;
        int   yt1  = -1;
        if (t < NN - NT) {                     // t < 128 -> k = t + 256
            cit1 = csmd[(size_t)i * NN + t + NT];
            yt1  = y[t + NT];
        }
        if (yt0 == yi && t != i) {
            int p = atomicAdd(&cnt, 1);
            cvals[p] = cit0; jidx[p] = t;
        }
        if (yt1 == yi && (t + NT) != i) {
            int p = atomicAdd(&cnt, 1);
            cvals[p] = cit1; jidx[p] = t + NT;
        }
        __syncthreads();
        const int c = cnt;
        float m0 = 0.f, m1 = 0.f;
        const float* invc0 = invd + t;
        const float* invc1 = invd + t + NT;
        for (int jj = 0; jj < c; ++jj) {
            const float cv = cvals[jj];
            const size_t off = (size_t)jidx[jj] * NN;
            m0 = fmaxf(m0, fmaxf(cit0 - cv, 0.f) * invc0[off]);
            if (t < NN - NT)
                m1 = fmaxf(m1, fmaxf(cit1 - cv, 0.f) * invc1[off]);
        }
        if (yt0 == yi) m0 = __builtin_inff();
        if (t >= NN - NT || yt1 == yi) m1 = __builtin_inff();
        red[t] = fminf(m0, m1);
        __syncthreads();
        if (t < 128) red[t] = fminf(red[t], red[t + 128]);
        __syncthreads();
        if (t < 64) {
            float v = fminf(red[t], red[t + 64]);
#pragma unroll
            for (int off = 32; off > 0; off >>= 1)
                v = fminf(v, __shfl_down(v, off));
            if (t == 0) out[i] = v;
        }
        __syncthreads();               // protect cvals/jidx/red/cnt for next i
    }
}

extern "C" void kernel_launch(void* const* d_in, const int* in_sizes, int n_in,
                              void* d_out, int out_size, void* d_ws, size_t ws_size,
                              hipStream_t stream) {
    const float* X = (const float*)d_in[0];
    const float* G = (const float*)d_in[1];
    const int*   y = (const int*)d_in[2];

    float* ws   = (float*)d_ws;
    float* A    = ws;                  // 384*128
    float* prod = A + NN * DD;         // 384
    float* p2   = prod + NN;           // 384
    float* csmd = p2 + NN;             // 384*384
    float* invd = csmd + NN * NN;      // 384*384
    float* out  = (float*)d_out;

    void* args[] = {(void*)&X, (void*)&G, (void*)&y, (void*)&A, (void*)&prod,
                    (void*)&p2, (void*)&csmd, (void*)&invd, (void*)&out};
    hipLaunchCooperativeKernel((void*)k_fused, dim3(NB), dim3(NT), args, 0, stream);
}

// Round 4
// 30.067 us; speedup vs baseline: 3.5960x; 3.5960x over previous
//
#include <hip/hip_runtime.h>
#include <math.h>

#define NN 384
#define DD 128
#define NTILE (NN / 16)   // 24
#define EPSF 1e-6f

// K1: per-row  B_i = x_i G^T  (LDS only),  A_i = B_i G,
//     prod[i] = B_i.B_i (== x_i M x_i),  p2[i] = A_i.A_i
// 384 blocks x 128 threads.
__global__ void __launch_bounds__(128) k_A(const float* __restrict__ X,
                                           const float* __restrict__ G,
                                           float* __restrict__ A,
                                           float* __restrict__ prod,
                                           float* __restrict__ p2) {
    __shared__ float Xi[DD];
    __shared__ float Bs[DD];
    __shared__ float rp[2], rq[2];
    const int i = blockIdx.x;
    const int t = threadIdx.x;

    if (t < DD / 4) ((float4*)Xi)[t] = ((const float4*)(X + (size_t)i * DD))[t];
    __syncthreads();

    // pass 1: B[t] = sum_d Xi[d] * G[t][d]
    float b = 0.f;
    const float* gr = G + (size_t)t * DD;
#pragma unroll
    for (int d = 0; d < DD; d += 4) {
        float4 g = *(const float4*)(gr + d);
        b = fmaf(g.x, Xi[d + 0], b);
        b = fmaf(g.y, Xi[d + 1], b);
        b = fmaf(g.z, Xi[d + 2], b);
        b = fmaf(g.w, Xi[d + 3], b);
    }
    Bs[t] = b;
    __syncthreads();

    // pass 2: A[t] = sum_c B[c] * G[c][t]   (coalesced G reads)
    float a = 0.f;
#pragma unroll 8
    for (int c = 0; c < DD; ++c)
        a = fmaf(Bs[c], G[(size_t)c * DD + t], a);
    A[(size_t)i * DD + t] = a;

    // reductions: prod = sum b^2, p2 = sum a^2
    float pp = b * b, qq = a * a;
#pragma unroll
    for (int off = 32; off > 0; off >>= 1) {
        pp += __shfl_down(pp, off);
        qq += __shfl_down(qq, off);
    }
    if ((t & 63) == 0) { rp[t >> 6] = pp; rq[t >> 6] = qq; }
    __syncthreads();
    if (t == 0) { prod[i] = rp[0] + rp[1]; p2[i] = rq[0] + rq[1]; }
}

// K2: csmd[i][k] = prod[i]+prod[k]-2*dot(A_i,X_k)
//     invd[i][k] = 1/max(2*sqrt(max(p2[i]+p2[k]-2*dot(A_i,A_k), eps)), eps)
// Symmetric: compute upper-triangle tiles only; mirror via LDS transpose.
__global__ void __launch_bounds__(256) k_csmd(const float* __restrict__ X,
                                              const float* __restrict__ A,
                                              const float* __restrict__ prod,
                                              const float* __restrict__ p2,
                                              float* __restrict__ csmd,
                                              float* __restrict__ invd) {
    const int ti = blockIdx.y, tk = blockIdx.x;
    if (ti > tk) return;                 // lower triangle: exit immediately
    __shared__ float Ai[16][20], Xk[16][20], Ak[16][20];
    __shared__ float Tc[16][17], Tv[16][17];
    const int tx = threadIdx.x, ty = threadIdx.y;
    const int k0 = tk * 16, i0 = ti * 16;
    float dA = 0.f, dAA = 0.f;
    for (int d0 = 0; d0 < DD; d0 += 16) {
        Ai[ty][tx] = A[(size_t)(i0 + ty) * DD + d0 + tx];
        Xk[ty][tx] = X[(size_t)(k0 + ty) * DD + d0 + tx];
        Ak[ty][tx] = A[(size_t)(k0 + ty) * DD + d0 + tx];
        __syncthreads();
#pragma unroll
        for (int t4 = 0; t4 < 16; t4 += 4) {
            float4 aa = *(const float4*)&Ai[ty][t4];
            float4 xx = *(const float4*)&Xk[tx][t4];
            float4 ak = *(const float4*)&Ak[tx][t4];
            dA  = fmaf(aa.x, xx.x, dA);  dA  = fmaf(aa.y, xx.y, dA);
            dA  = fmaf(aa.z, xx.z, dA);  dA  = fmaf(aa.w, xx.w, dA);
            dAA = fmaf(aa.x, ak.x, dAA); dAA = fmaf(aa.y, ak.y, dAA);
            dAA = fmaf(aa.z, ak.z, dAA); dAA = fmaf(aa.w, ak.w, dAA);
        }
        __syncthreads();
    }
    const int i = i0 + ty, k = k0 + tx;
    const float c1 = prod[i] + prod[k] - 2.f * dA;
    const float c2 = p2[i] + p2[k] - 2.f * dAA;
    const float inv = 1.f / fmaxf(2.f * sqrtf(fmaxf(c2, EPSF)), EPSF);
    csmd[(size_t)i * NN + k] = c1;
    invd[(size_t)i * NN + k] = inv;
    if (ti != tk) {                      // mirror tile, coalesced via LDS transpose
        Tc[tx][ty] = c1;
        Tv[tx][ty] = inv;
        __syncthreads();
        csmd[(size_t)(k0 + ty) * NN + i0 + tx] = Tc[ty][tx];
        invd[(size_t)(k0 + ty) * NN + i0 + tx] = Tv[ty][tx];
    }
}

// K3: out[i] = min_{k: y[k]!=y[i]} max_{j: y[j]==y[i], j!=i} relu(csmd[i,k]-csmd[i,j]) * invd[j,k]
__global__ void __launch_bounds__(NN) k_cube(const float* __restrict__ csmd,
                                             const float* __restrict__ invd,
                                             const int* __restrict__ y,
                                             float* __restrict__ out) {
    __shared__ float cvals[NN];
    __shared__ int   jidx[NN];
    __shared__ float red[NN];
    __shared__ int   cnt;
    const int i = blockIdx.x;
    const int t = threadIdx.x;
    const int yi = y[i];
    if (t == 0) cnt = 0;
    __syncthreads();
    const float cit = csmd[(size_t)i * NN + t];
    const int yt = y[t];
    if (yt == yi && t != i) {
        int p = atomicAdd(&cnt, 1);
        cvals[p] = cit;
        jidx[p]  = t;
    }
    __syncthreads();
    const int c = cnt;
    float m = 0.f;
    const float* invcol = invd + t;
    for (int jj = 0; jj < c; ++jj) {
        float dlt = fmaxf(cit - cvals[jj], 0.f);
        m = fmaxf(m, dlt * invcol[(size_t)jidx[jj] * NN]);
    }
    if (yt == yi) m = __builtin_inff();
    red[t] = m;
    __syncthreads();
    if (t < 128) red[t] = fminf(red[t], fminf(red[t + 128], red[t + 256]));
    __syncthreads();
    if (t < 64) {
        float v = fminf(red[t], red[t + 64]);
#pragma unroll
        for (int off = 32; off > 0; off >>= 1)
            v = fminf(v, __shfl_down(v, off));
        if (t == 0) out[i] = v;
    }
}

extern "C" void kernel_launch(void* const* d_in, const int* in_sizes, int n_in,
                              void* d_out, int out_size, void* d_ws, size_t ws_size,
                              hipStream_t stream) {
    const float* X = (const float*)d_in[0];
    const float* G = (const float*)d_in[1];
    const int*   y = (const int*)d_in[2];

    float* ws   = (float*)d_ws;
    float* A    = ws;                  // 384*128
    float* prod = A + NN * DD;         // 384
    float* p2   = prod + NN;           // 384
    float* csmd = p2 + NN;             // 384*384
    float* invd = csmd + NN * NN;      // 384*384
    float* out  = (float*)d_out;

    k_A   <<<dim3(NN), dim3(DD), 0, stream>>>(X, G, A, prod, p2);
    k_csmd<<<dim3(NTILE, NTILE), dim3(16, 16), 0, stream>>>(X, A, prod, p2, csmd, invd);
    k_cube<<<dim3(NN), dim3(NN), 0, stream>>>(csmd, invd, y, out);
}